// Round 10
// baseline (238.793 us; speedup 1.0000x reference)
//
#include <hip/hip_runtime.h>

#define B_ 32
#define C_ 512
#define HW_ 4096
#define N_ 80

typedef __bf16 bf16x8 __attribute__((ext_vector_type(8)));
typedef __bf16 bf16x4 __attribute__((ext_vector_type(4)));
typedef float f32x4 __attribute__((ext_vector_type(4)));
typedef unsigned short u16x8 __attribute__((ext_vector_type(8)));

__device__ __forceinline__ void gload_lds16(const void* g, void* l) {
  __builtin_amdgcn_global_load_lds((const __attribute__((address_space(1))) void*)g,
                                   (__attribute__((address_space(3))) void*)l, 16, 0, 0);
}

#define VMCNT(n) asm volatile("s_waitcnt vmcnt(" #n ")" ::: "memory")
#define LGKM0() asm volatile("s_waitcnt lgkmcnt(0)" ::: "memory")
#define SBAR() asm volatile("s_barrier" ::: "memory")
#define MFMA(a, b, c) __builtin_amdgcn_mfma_f32_16x16x32_bf16(a, b, c, 0, 0, 0)

// ---------------------------------------------------------------------------
// K0: refragment W -> Wfrag bf16: unit t = (cs*5+nf)*64+lane holds
//     W[nf*16+(lane&15)][cs*32+(lane>>4)*8 .. +8]   (MFMA B-operand layout)
// ---------------------------------------------------------------------------
__global__ __launch_bounds__(256) void k0_wfrag(const float* __restrict__ W,
                                                __bf16* __restrict__ Wfrag) {
  const int t = blockIdx.x * 256 + threadIdx.x;
  if (t >= 16 * 5 * 64) return;
  const int cs = t / 320, rem = t % 320;
  const int nf = rem >> 6, lane = rem & 63;
  const int n = nf * 16 + (lane & 15);
  const int c = cs * 32 + (lane >> 4) * 8;
  const float* wp = W + (size_t)n * C_ + c;
  bf16x8 v;
#pragma unroll
  for (int i = 0; i < 8; ++i) v[i] = (__bf16)wp[i];
  *(bf16x8*)(Wfrag + (size_t)t * 8) = v;
}

__global__ __launch_bounds__(256) void kz_zero(float* __restrict__ denom) {
  const int i = blockIdx.x * 256 + threadIdx.x;
  if (i < B_ * N_) denom[i] = 0.f;
}

// ---------------------------------------------------------------------------
// KF: fused. Block = (b, hs in [0,8)): h-slice of 512. 8 waves (512 thr).
// Per 64-h chunk hc:
//   8 cc-iters (64 c each): [vmcnt(2); bar; wf-prefetch; stage(s+2);
//     logits-MFMA from ftile cols; convert ftile->pvbuf bf16 (XOR swz)]
//   phaseB: exp(lacc)->elds (XOR swz) + reg denom partials
//   phaseC: PV MFMA pvbuf x elds -> persistent acc[4][5]
// Epilogue: part[hs][b][n][c] f32 + denom atomics.
// LDS: ftile 3x16KB + pvbuf 64KB + elds 10KB = 122 KB -> 1 block/CU.
// Waves: (hq = w>>1) h-band for logits; ng = w&1 splits nf {0,1,2}|{3,4};
// PV: wave w owns c-range w*64.
// ---------------------------------------------------------------------------
#define STAGE(S)                                                                  \
  do {                                                                            \
    const int slot_ = (S) % 3;                                                    \
    const int hc_ = (S) >> 3, cc_ = (S) & 7;                                      \
    const float* g0_ =                                                            \
        fb + (size_t)(cc_ * 64 + srow) * HW_ + hbase + hc_ * 64 + scol4;          \
    gload_lds16(g0_, (char*)ftile + slot_ * 16384 + w * 1024);                    \
    gload_lds16(g0_ + (size_t)32 * HW_,                                           \
                (char*)ftile + slot_ * 16384 + 8192 + w * 1024);                  \
  } while (0)

#define WFLOAD(DST, CC)                                                           \
  do {                                                                            \
    _Pragma("unroll") for (int ks_ = 0; ks_ < 2; ++ks_)                           \
    _Pragma("unroll") for (int nf_ = 0; nf_ < 3; ++nf_)                           \
      if (nf_ < nfcnt)                                                            \
        DST[ks_][nf_] = *(const u16x8*)(Wfrag +                                   \
            ((size_t)(((CC)*2 + ks_) * 5 + nfbase + nf_) * 64 + lane) * 8);       \
  } while (0)

#define LOGITS(S, WU)                                                             \
  do {                                                                            \
    const float* tb_ = (const float*)((char*)ftile + ((S) % 3) * 16384);          \
    _Pragma("unroll") for (int ks_ = 0; ks_ < 2; ++ks_) {                         \
      bf16x8 af_;                                                                 \
      _Pragma("unroll") for (int i_ = 0; i_ < 8; ++i_)                            \
        af_[i_] = (__bf16)tb_[(ks_ * 32 + quad * 8 + i_) * 64 + hq * 16 + l16];   \
      _Pragma("unroll") for (int nf_ = 0; nf_ < 3; ++nf_)                         \
        if (nf_ < nfcnt) {                                                        \
          const bf16x8 bf_ = __builtin_bit_cast(bf16x8, WU[ks_][nf_]);            \
          lacc[nf_] = MFMA(af_, bf_, lacc[nf_]);                                  \
        }                                                                         \
    }                                                                             \
  } while (0)

#define CONVERT(S, CC)                                                            \
  do {                                                                            \
    const float* sb_ = (const float*)((char*)ftile + ((S) % 3) * 16384);          \
    const int r_ = tid >> 3, p_ = tid & 7;                                        \
    const f32x4 v0_ = *(const f32x4*)(sb_ + r_ * 64 + p_ * 8);                    \
    const f32x4 v1_ = *(const f32x4*)(sb_ + r_ * 64 + p_ * 8 + 4);                \
    bf16x8 o_;                                                                    \
    o_[0] = (__bf16)v0_[0]; o_[1] = (__bf16)v0_[1];                               \
    o_[2] = (__bf16)v0_[2]; o_[3] = (__bf16)v0_[3];                               \
    o_[4] = (__bf16)v1_[0]; o_[5] = (__bf16)v1_[1];                               \
    o_[6] = (__bf16)v1_[2]; o_[7] = (__bf16)v1_[3];                               \
    *(bf16x8*)&pvbuf[((CC)*64 + r_) * 64 + (p_ ^ (r_ & 7)) * 8] = o_;             \
  } while (0)

#define ITER(HC, CC, WU, WL)                                                      \
  do {                                                                            \
    VMCNT(2);                                                                     \
    SBAR();                                                                       \
    WFLOAD(WL, ((CC) + 1) & 7);                                                   \
    if ((HC)*8 + (CC) + 2 < 64) STAGE((HC)*8 + (CC) + 2);                         \
    LOGITS((HC)*8 + (CC), WU);                                                    \
    CONVERT((HC)*8 + (CC), CC);                                                   \
  } while (0)

#define PHASEB()                                                                  \
  do {                                                                            \
    _Pragma("unroll") for (int nf_ = 0; nf_ < 3; ++nf_) if (nf_ < nfcnt) {        \
      const float e0_ = __expf(lacc[nf_][0]);                                     \
      const float e1_ = __expf(lacc[nf_][1]);                                     \
      const float e2_ = __expf(lacc[nf_][2]);                                     \
      const float e3_ = __expf(lacc[nf_][3]);                                     \
      dsum[nf_] += e0_ + e1_ + e2_ + e3_;                                         \
      bf16x4 pk_;                                                                 \
      pk_[0] = (__bf16)e0_; pk_[1] = (__bf16)e1_;                                 \
      pk_[2] = (__bf16)e2_; pk_[3] = (__bf16)e3_;                                 \
      const int n_ = (nfbase + nf_) * 16 + l16;                                   \
      const int pp_ = (hq * 2 + (quad >> 1)) ^ (l16 & 7);                         \
      *(bf16x4*)&elds[n_ * 64 + pp_ * 8 + (quad & 1) * 4] = pk_;                  \
      lacc[nf_] = zero;                                                           \
    }                                                                             \
  } while (0)

#define PHASEC()                                                                  \
  do {                                                                            \
    _Pragma("unroll") for (int ks_ = 0; ks_ < 2; ++ks_) {                         \
      bf16x8 a_[4];                                                               \
      _Pragma("unroll") for (int cf_ = 0; cf_ < 4; ++cf_) {                       \
        const int c_ = w * 64 + cf_ * 16 + l16;                                   \
        a_[cf_] = *(const bf16x8*)&pvbuf[c_ * 64 + ((ks_ * 4 + quad) ^ (l16 & 7)) * 8]; \
      }                                                                           \
      _Pragma("unroll") for (int nf_ = 0; nf_ < 5; ++nf_) {                       \
        const int n_ = nf_ * 16 + l16;                                            \
        const bf16x8 b_ =                                                         \
            *(const bf16x8*)&elds[n_ * 64 + ((ks_ * 4 + quad) ^ (l16 & 7)) * 8];  \
        _Pragma("unroll") for (int cf_ = 0; cf_ < 4; ++cf_)                       \
          acc[cf_][nf_] = MFMA(a_[cf_], b_, acc[cf_][nf_]);                       \
      }                                                                           \
    }                                                                             \
  } while (0)

__global__ __launch_bounds__(512, 2) void kf_fused(const float* __restrict__ feats,
                                                   const __bf16* __restrict__ Wfrag,
                                                   float* __restrict__ part,
                                                   float* __restrict__ denom) {
  __shared__ float ftile[3][64 * 64];   // 48 KB staging (linear)
  __shared__ __bf16 pvbuf[512 * 64];    // 64 KB feats bf16, XOR p^(c&7)
  __shared__ __bf16 elds[80 * 64];      // 10 KB E bf16, XOR p^(n&7)

  const int tid = threadIdx.x;
  const int lane = tid & 63, w = tid >> 6;
  const int quad = lane >> 4, l16 = lane & 15;
  const int hq = w >> 1, ng = w & 1;
  const int nfbase = ng ? 3 : 0, nfcnt = ng ? 2 : 3;
  const int bid = blockIdx.x;
  const int b = bid & 31, hs = bid >> 5;
  const float* fb = feats + (size_t)b * (C_ * HW_);
  const int hbase = hs * 512;
  const int srow = tid >> 4;          // staging c-row (and +32)
  const int scol4 = (tid & 15) * 4;   // staging h-offset (floats)

  const f32x4 zero = {0.f, 0.f, 0.f, 0.f};
  f32x4 acc[4][5];
#pragma unroll
  for (int cf = 0; cf < 4; ++cf)
#pragma unroll
    for (int nf = 0; nf < 5; ++nf) acc[cf][nf] = zero;
  f32x4 lacc[3];
#pragma unroll
  for (int i = 0; i < 3; ++i) lacc[i] = zero;
  float dsum[3] = {0.f, 0.f, 0.f};

  u16x8 wfA[2][3], wfB[2][3];
  // prologue FIFO: wf0 BEFORE stages so vmcnt(2) covers it at iter 0
  WFLOAD(wfA, 0);
  STAGE(0);
  STAGE(1);

  for (int hc = 0; hc < 8; ++hc) {
    ITER(hc, 0, wfA, wfB);
    ITER(hc, 1, wfB, wfA);
    ITER(hc, 2, wfA, wfB);
    ITER(hc, 3, wfB, wfA);
    ITER(hc, 4, wfA, wfB);
    ITER(hc, 5, wfB, wfA);
    ITER(hc, 6, wfA, wfB);
    if (hc < 7) {
      ITER(hc, 7, wfB, wfA);
    } else {
      VMCNT(0);
      SBAR();
      LOGITS(63, wfB);
      CONVERT(63, 7);
    }
    LGKM0();
    SBAR();   // conversions (all cc) + logits done -> phaseB may write elds
    PHASEB();
    LGKM0();
    SBAR();   // elds ready -> PV
    PHASEC();
    // next iteration's vmcnt+barrier separates PV reads from next conversions
  }

  // epilogue: partial store + denom atomics (once per block)
  float* pb = part + (size_t)hs * (B_ * N_ * C_) + (size_t)b * (N_ * C_);
#pragma unroll
  for (int cf = 0; cf < 4; ++cf)
#pragma unroll
    for (int nf = 0; nf < 5; ++nf) {
      const int n = nf * 16 + l16;
      float4 v;
      v.x = acc[cf][nf][0]; v.y = acc[cf][nf][1];
      v.z = acc[cf][nf][2]; v.w = acc[cf][nf][3];
      *(float4*)(pb + (size_t)n * C_ + w * 64 + cf * 16 + quad * 4) = v;
    }
#pragma unroll
  for (int nf = 0; nf < 3; ++nf)
    if (nf < nfcnt) {
      float s = dsum[nf];
      s += __shfl_xor(s, 16);
      s += __shfl_xor(s, 32);
      if (lane < 16) atomicAdd(denom + b * N_ + (nfbase + nf) * 16 + lane, s);
    }
}

// ---------------------------------------------------------------------------
// K4: out = (sum_hs part[hs]) / denom[b][n]
// ---------------------------------------------------------------------------
__global__ __launch_bounds__(256) void k4_reduce(const float* __restrict__ part,
                                                 const float* __restrict__ denom,
                                                 float* __restrict__ out) {
  const size_t i = ((size_t)blockIdx.x * 256 + threadIdx.x) * 4;
  if (i >= (size_t)B_ * N_ * C_) return;
  float4 s = *(const float4*)(part + i);
#pragma unroll
  for (int hz = 1; hz < 8; ++hz) {
    const float4 v = *(const float4*)(part + (size_t)hz * (B_ * N_ * C_) + i);
    s.x += v.x; s.y += v.y; s.z += v.z; s.w += v.w;
  }
  const float r = 1.0f / denom[i >> 9];
  s.x *= r; s.y *= r; s.z *= r; s.w *= r;
  *(float4*)(out + i) = s;
}

extern "C" void kernel_launch(void* const* d_in, const int* in_sizes, int n_in,
                              void* d_out, int out_size, void* d_ws, size_t ws_size,
                              hipStream_t stream) {
  (void)in_sizes; (void)n_in; (void)out_size; (void)ws_size;
  const float* feats = (const float*)d_in[0];
  const float* Wm = (const float*)d_in[1];
  float* out = (float*)d_out;

  __bf16* Wfrag = (__bf16*)d_ws;                       // 80 KB
  float* part = (float*)((char*)d_ws + 81920);         // 8 x 5.24 MB = 42 MB
  float* denom = part + (size_t)8 * B_ * N_ * C_;      // 10 KB

  hipLaunchKernelGGL(k0_wfrag, dim3(20), dim3(256), 0, stream, Wm, Wfrag);
  hipLaunchKernelGGL(kz_zero, dim3(10), dim3(256), 0, stream, denom);
  hipLaunchKernelGGL(kf_fused, dim3(256), dim3(512), 0, stream, feats, Wfrag, part, denom);
  const int n4 = (B_ * N_ * C_) / 4;
  hipLaunchKernelGGL(k4_reduce, dim3(n4 / 256), dim3(256), 0, stream, part, denom, out);
}

// Round 11
// 122.333 us; speedup vs baseline: 1.9520x; 1.9520x over previous
//
#include <hip/hip_runtime.h>

#define B_ 32
#define C_ 512
#define HW_ 4096
#define N_ 80

typedef __bf16 bf16x8 __attribute__((ext_vector_type(8)));
typedef __bf16 bf16x4 __attribute__((ext_vector_type(4)));
typedef float f32x4 __attribute__((ext_vector_type(4)));
typedef unsigned short u16x8 __attribute__((ext_vector_type(8)));

__device__ __forceinline__ void gload_lds16(const void* g, void* l) {
  __builtin_amdgcn_global_load_lds((const __attribute__((address_space(1))) void*)g,
                                   (__attribute__((address_space(3))) void*)l, 16, 0, 0);
}

#define VMCNT(n) asm volatile("s_waitcnt vmcnt(" #n ")" ::: "memory")
#define SBAR() asm volatile("s_barrier" ::: "memory")

// ---------------------------------------------------------------------------
// K0: refragment W -> Wfrag bf16 (unit t = (cs*5+nf)*64+lane holds
//     W[nf*16+(lane&15)][cs*32+(lane>>4)*8 .. +8]) AND zero denom.
// ---------------------------------------------------------------------------
__global__ __launch_bounds__(256) void k0_wfrag(const float* __restrict__ W,
                                                __bf16* __restrict__ Wfrag,
                                                float* __restrict__ denom) {
  const int t = blockIdx.x * 256 + threadIdx.x;
  if (t < B_ * N_) denom[t] = 0.f;
  if (t >= 16 * 5 * 64) return;
  const int cs = t / 320, rem = t % 320;
  const int nf = rem >> 6, lane = rem & 63;
  const int n = nf * 16 + (lane & 15);
  const int c = cs * 32 + (lane >> 4) * 8;
  const float* wp = W + (size_t)n * C_ + c;
  bf16x8 v;
#pragma unroll
  for (int i = 0; i < 8; ++i) v[i] = (__bf16)wp[i];
  *(bf16x8*)(Wfrag + (size_t)t * 8) = v;
}

// ---------------------------------------------------------------------------
// K1: E[b][n][h] = exp(sum_c feats[b][c][h] * W[n][c]); denom += row sums.
// Counted-vmcnt pipeline (R9, unchanged): 3 buffers [32c][128h], depth-2
// stage prefetch + 1-ahead Wfrag register prefetch (named sets).
// Iter = [vmcnt(9); s_barrier; load wf(t+1); stage(t+2); compute(t)].
// Grid (HW/128, B) = 1024 blocks, 4 waves, 3 blocks/CU (48 KB LDS).
// ---------------------------------------------------------------------------
#define K1_STAGE(CS, SLOT)                                                      \
  {                                                                             \
    _Pragma("unroll") for (int j = 0; j < 4; ++j) {                             \
      const int d = j * 256 + tid;                                              \
      const int r = d >> 5, p = d & 31;                                         \
      gload_lds16(fb + (size_t)((CS)*32 + r) * HW_ + htile0 + p * 4,            \
                  (char*)tile + (SLOT)*16384 + (j * 256 + wave * 64) * 16);     \
    }                                                                           \
  }

#define K1_WLOAD(W, CS)                                                         \
  {                                                                             \
    _Pragma("unroll") for (int nf = 0; nf < 5; ++nf)                            \
        W[nf] = *(const u16x8*)(Wfrag + ((size_t)((CS)*5 + nf) * 64 + lane) * 8); \
  }

#define K1_COMPUTE(T, WU)                                                       \
  {                                                                             \
    const float* tb = (const float*)((char*)tile + ((T) % 3) * 16384);          \
    bf16x8 afr[2];                                                              \
    _Pragma("unroll") for (int hf = 0; hf < 2; ++hf) {                          \
      const int col = wave * 32 + hf * 16 + l16;                                \
      _Pragma("unroll") for (int i = 0; i < 8; ++i)                             \
          afr[hf][i] = (__bf16)tb[(quad * 8 + i) * 128 + col];                  \
    }                                                                           \
    _Pragma("unroll") for (int nf = 0; nf < 5; ++nf) {                          \
      const bf16x8 bfr = __builtin_bit_cast(bf16x8, WU[nf]);                    \
      acc[0][nf] = __builtin_amdgcn_mfma_f32_16x16x32_bf16(afr[0], bfr, acc[0][nf], 0, 0, 0); \
      acc[1][nf] = __builtin_amdgcn_mfma_f32_16x16x32_bf16(afr[1], bfr, acc[1][nf], 0, 0, 0); \
    }                                                                           \
  }

#define K1_ITER(T, WU, WL)                                                      \
  {                                                                             \
    VMCNT(9); SBAR();                                                           \
    K1_WLOAD(WL, (T) + 1);                                                      \
    if ((T) + 2 < 16) K1_STAGE((T) + 2, ((T) + 2) % 3);                         \
    K1_COMPUTE(T, WU);                                                          \
  }

__global__ __launch_bounds__(256, 3) void k1_logits(const float* __restrict__ feats,
                                                    const __bf16* __restrict__ Wfrag,
                                                    __bf16* __restrict__ E,
                                                    float* __restrict__ denom) {
  __shared__ float tile[3][32 * 128];  // 48 KB
  const int tid = threadIdx.x;
  const int lane = tid & 63, wave = tid >> 6;
  const int quad = lane >> 4, l16 = lane & 15;
  const int b = blockIdx.y;
  const int htile0 = blockIdx.x * 128;
  const float* fb = feats + (size_t)b * (C_ * HW_);

  const f32x4 zero = {0.f, 0.f, 0.f, 0.f};
  f32x4 acc[2][5];
#pragma unroll
  for (int hf = 0; hf < 2; ++hf)
#pragma unroll
    for (int nf = 0; nf < 5; ++nf) acc[hf][nf] = zero;

  u16x8 wfA[5], wfB[5];
  // prologue (order fixes FIFO accounting): s0, wf0, s1
  K1_STAGE(0, 0);
  K1_WLOAD(wfA, 0);
  K1_STAGE(1, 1);

  for (int t = 0; t < 14; t += 2) {
    K1_ITER(t, wfA, wfB);
    K1_ITER(t + 1, wfB, wfA);
  }
  K1_ITER(14, wfA, wfB);   // loads wf15 -> wfB; no stage(16)
  VMCNT(5); SBAR();
  K1_COMPUTE(15, wfB);

  // Epilogue: exp, bf16 E store, per-row denom atomics.
#pragma unroll
  for (int nf = 0; nf < 5; ++nf) {
    const int n = nf * 16 + l16;
    float s = 0.f;
#pragma unroll
    for (int hf = 0; hf < 2; ++hf) {
      bf16x4 pk;
#pragma unroll
      for (int j = 0; j < 4; ++j) {
        const float e = __expf(acc[hf][nf][j]);
        s += e;
        pk[j] = (__bf16)e;
      }
      const int h = htile0 + wave * 32 + hf * 16 + quad * 4;
      *(bf16x4*)(E + (size_t)(b * N_ + n) * HW_ + h) = pk;
    }
    s += __shfl_xor(s, 16);
    s += __shfl_xor(s, 32);
    if (lane < 16) atomicAdd(denom + b * N_ + nf * 16 + lane, s);
  }
}

// ---------------------------------------------------------------------------
// K3: out[b][n][c] = (sum_h E[b][n][h] * feats[b][c][h]) / denom[b][n]
// HSPLIT=1: full h-range per block; writes final output (k4/part deleted).
// Counted-vmcnt pipeline (R9 recipe): 4 buffers {fA [32c][64h] f32 8KB,
// fB [80n][64h] bf16 10KB}, depth-3, 5 uniform gload_lds/wave/stage.
// XOR source-swizzle: fA phys p holds logical p^(r&15); fB p^(r&7).
// Iter = [vmcnt(10); s_barrier; stage(t+3); compute(t)]; tails 10/5/0.
// XCD-chunked remap (512 = 8*64): 16 c-blocks of one b share an XCD L2.
// Grid 512 flat, 4 waves, 2 blocks/CU (72 KB LDS).
// ---------------------------------------------------------------------------
#define K3_STAGE(TK, SLOT)                                                      \
  {                                                                             \
    const int h0 = (TK)*64;                                                     \
    _Pragma("unroll") for (int j = 0; j < 2; ++j) {                             \
      const int d = j * 256 + tid;                                              \
      const int r = d >> 4, p = d & 15;                                         \
      gload_lds16(fb + (size_t)(c0 + r) * HW_ + h0 + ((p ^ (r & 15)) << 2),     \
                  (char*)fA + (SLOT)*8192 + (j * 256 + wave * 64) * 16);        \
    }                                                                           \
    _Pragma("unroll") for (int j = 0; j < 2; ++j) {                             \
      const int d = j * 256 + tid;                                              \
      const int r = d >> 3, p = d & 7;                                          \
      gload_lds16(eb + (size_t)r * HW_ + h0 + ((p ^ (r & 7)) << 3),             \
                  (char*)fB + (SLOT)*10240 + (j * 256 + wave * 64) * 16);       \
    }                                                                           \
    {                                                                           \
      const int d = 512 + (wave & 1) * 64 + lane;                               \
      const int r = d >> 3, p = d & 7;                                          \
      gload_lds16(eb + (size_t)r * HW_ + h0 + ((p ^ (r & 7)) << 3),             \
                  (char*)fB + (SLOT)*10240 + (512 + (wave & 1) * 64) * 16);     \
    }                                                                           \
  }

#define K3_COMPUTE(T)                                                           \
  {                                                                             \
    const float* A = (const float*)((char*)fA + ((T) % 4) * 8192);              \
    const __bf16* Bv = (const __bf16*)((char*)fB + ((T) % 4) * 10240);          \
    _Pragma("unroll") for (int ks = 0; ks < 2; ++ks) {                          \
      const int u0 = (ks * 8 + quad * 2) ^ l16;                                 \
      const int u1 = (ks * 8 + quad * 2 + 1) ^ l16;                             \
      const f32x4 va = *(const f32x4*)&A[rA * 64 + u0 * 4];                     \
      const f32x4 vb = *(const f32x4*)&A[rA * 64 + u1 * 4];                     \
      bf16x8 af;                                                                \
      af[0] = (__bf16)va[0]; af[1] = (__bf16)va[1];                             \
      af[2] = (__bf16)va[2]; af[3] = (__bf16)va[3];                             \
      af[4] = (__bf16)vb[0]; af[5] = (__bf16)vb[1];                             \
      af[6] = (__bf16)vb[2]; af[7] = (__bf16)vb[3];                             \
      _Pragma("unroll") for (int nfl = 0; nfl < 3; ++nfl) {                     \
        if (nfl >= nfcnt) break;                                                \
        const int n = (nfbase + nfl) * 16 + l16;                                \
        const int ub = (ks * 4 + quad) ^ (l16 & 7);                             \
        const u16x8 bv = *(const u16x8*)&Bv[n * 64 + ub * 8];                   \
        const bf16x8 bfr = __builtin_bit_cast(bf16x8, bv);                      \
        acc[nfl] = __builtin_amdgcn_mfma_f32_16x16x32_bf16(af, bfr, acc[nfl], 0, 0, 0); \
      }                                                                         \
    }                                                                           \
  }

__global__ __launch_bounds__(256, 2) void k3_pool(const float* __restrict__ feats,
                                                  const __bf16* __restrict__ E,
                                                  const float* __restrict__ denom,
                                                  float* __restrict__ out) {
  __shared__ float fA[4][32 * 64];    // 32 KB
  __shared__ __bf16 fB[4][80 * 64];   // 40 KB
  const int tid = threadIdx.x;
  const int lane = tid & 63, wave = tid >> 6;
  const int quad = lane >> 4, l16 = lane & 15;
  const int cf = wave & 1, ng = wave >> 1;
  const int nfbase = ng ? 3 : 0, nfcnt = ng ? 2 : 3;

  // XCD-chunked remap (bijective: 512 = 8 * 64)
  const int wg = blockIdx.x;
  const int nid = (wg & 7) * 64 + (wg >> 3);
  const int b = nid >> 4, cx = nid & 15;
  const int c0 = cx * 32;

  const float* fb = feats + (size_t)b * (C_ * HW_);
  const __bf16* eb = E + (size_t)b * N_ * HW_;
  const int rA = cf * 16 + l16;

  const f32x4 zero = {0.f, 0.f, 0.f, 0.f};
  f32x4 acc[3];
#pragma unroll
  for (int i = 0; i < 3; ++i) acc[i] = zero;

  K3_STAGE(0, 0);
  K3_STAGE(1, 1);
  K3_STAGE(2, 2);

  for (int t = 0; t < 61; ++t) {
    VMCNT(10); SBAR();
    K3_STAGE(t + 3, (t + 3) & 3);
    K3_COMPUTE(t);
  }
  VMCNT(10); SBAR(); K3_COMPUTE(61);
  VMCNT(5);  SBAR(); K3_COMPUTE(62);
  VMCNT(0);  SBAR(); K3_COMPUTE(63);

  // Epilogue: divide by denom, write final out.
#pragma unroll
  for (int nfl = 0; nfl < 3; ++nfl) {
    if (nfl >= nfcnt) break;
    const int n = (nfbase + nfl) * 16 + l16;
    const float r = 1.0f / denom[b * N_ + n];
    float4 v;
    v.x = acc[nfl][0] * r; v.y = acc[nfl][1] * r;
    v.z = acc[nfl][2] * r; v.w = acc[nfl][3] * r;
    *(float4*)(out + (size_t)(b * N_ + n) * C_ + c0 + cf * 16 + quad * 4) = v;
  }
}

extern "C" void kernel_launch(void* const* d_in, const int* in_sizes, int n_in,
                              void* d_out, int out_size, void* d_ws, size_t ws_size,
                              hipStream_t stream) {
  (void)in_sizes; (void)n_in; (void)out_size; (void)ws_size;
  const float* feats = (const float*)d_in[0];
  const float* Wm = (const float*)d_in[1];
  float* out = (float*)d_out;

  __bf16* E = (__bf16*)d_ws;                    // 21 MB
  __bf16* Wfrag = E + (size_t)B_ * N_ * HW_;    // 80 KB
  float* denom = (float*)(Wfrag + 16 * 5 * 64 * 8);  // 10 KB

  hipLaunchKernelGGL(k0_wfrag, dim3(20), dim3(256), 0, stream, Wm, Wfrag, denom);
  hipLaunchKernelGGL(k1_logits, dim3(HW_ / 128, B_), dim3(256), 0, stream, feats, Wfrag, E, denom);
  hipLaunchKernelGGL(k3_pool, dim3(512), dim3(256), 0, stream, feats, E, denom, out);
}